// Round 1
// baseline (1790.467 us; speedup 1.0000x reference)
//
#include <hip/hip_runtime.h>
#include <cstdint>
#include <cstddef>
#include <cfloat>

#define N_NODES 16384
#define HID 128
#define NGRAPH 64

typedef __attribute__((ext_vector_type(8))) short bf16x8;
typedef __attribute__((ext_vector_type(4))) float f32x4;

__device__ __forceinline__ unsigned int f2bf(float f) {
    union { float f; unsigned int u; } v; v.f = f;
    return (v.u + 0x7fffu + ((v.u >> 16) & 1u)) >> 16;
}
__device__ __forceinline__ float bf2f(unsigned int h) {
    union { unsigned int u; float f; } v; v.u = h << 16;
    return v.f;
}

// -------- kernel 1a: support = x @ W_gcn (f32 exact), row-major [k][c] --------
__global__ void support_kernel(const float* __restrict__ x,
                               const float* __restrict__ Wg,
                               float* __restrict__ sup) {
    const int idx = blockIdx.x * 256 + threadIdx.x;
    const int k = idx >> 7, c = idx & 127;
    const float* xr = x + (size_t)k * HID;
    float acc = 0.f;
#pragma unroll 8
    for (int i = 0; i < HID; i++) acc += xr[i] * Wg[i * HID + c];
    sup[idx] = acc;
}

// -------- kernel 1b: split support into bf16 hi/lo, TRANSPOSED sT[c][k] --------
__global__ void split_kernel(const float* __restrict__ sup,
                             unsigned short* __restrict__ sTh,
                             unsigned short* __restrict__ sTl) {
    __shared__ float tile[128 * 128];
    const int b = blockIdx.x, t = threadIdx.x;
    const float4* src = (const float4*)(sup + (size_t)b * 128 * 128);
    float4* dst = (float4*)tile;
#pragma unroll
    for (int i = 0; i < 16; i++) dst[i * 256 + t] = src[i * 256 + t];
    __syncthreads();
    const int c = t & 127;
    const bool lo = (t >= 128);
    unsigned short* outp = (lo ? sTl : sTh) + (size_t)c * N_NODES + b * 128;
#pragma unroll
    for (int k8 = 0; k8 < 128; k8 += 8) {
        unsigned int pk[4];
#pragma unroll
        for (int j = 0; j < 4; j++) {
            float v0 = tile[(k8 + 2 * j) * 128 + c];
            float v1 = tile[(k8 + 2 * j + 1) * 128 + c];
            unsigned int h0 = f2bf(v0), h1 = f2bf(v1);
            unsigned int r0 = lo ? f2bf(v0 - bf2f(h0)) : h0;
            unsigned int r1 = lo ? f2bf(v1 - bf2f(h1)) : h1;
            pk[j] = r0 | (r1 << 16);
        }
        *(uint4*)(outp + k8) = make_uint4(pk[0], pk[1], pk[2], pk[3]);
    }
}

// -------- kernel 2: partial = adj[:, krange] @ support[krange, :] (split-bf16 MFMA) --------
__global__ __launch_bounds__(256, 2) void gemm_kernel(
    const float* __restrict__ adj,
    const unsigned short* __restrict__ sTh,
    const unsigned short* __restrict__ sTl,
    float* __restrict__ part, int ksize) {
    __shared__ unsigned short ah[128 * 32];
    __shared__ unsigned short al[128 * 32];
    __shared__ unsigned short bh[128 * 32];
    __shared__ unsigned short bl[128 * 32];

    const int tid = threadIdx.x;
    const int m0 = blockIdx.x * 128;
    const int k0 = blockIdx.y * ksize;

    // adj staging: 4 passes x (row = p*32 + tid>>3, float4 col = tid&7)
    const int ar = tid >> 3;
    const int ac = tid & 7;
    const float* aptr = adj + (size_t)(m0 + ar) * N_NODES + k0 + ac * 4;
    const int aoff = ar * 32 + ac * 4;

    // b staging: 2 passes x (row = p*64 + tid>>2, 16B chunk = tid&3)
    const size_t bgo = (size_t)(tid >> 2) * N_NODES + k0 + (tid & 3) * 8;
    const int boff = tid * 8;

    const int lane = tid & 63;
    const int wv = tid >> 6;
    const int wm = wv >> 1, wn = wv & 1;
    const int quad = lane >> 4, l16 = lane & 15;
    const int afb = (wm * 64 + l16) * 32 + quad * 8;
    const int bfb = (wn * 64 + l16) * 32 + quad * 8;

    f32x4 acc[4][4];
#pragma unroll
    for (int i = 0; i < 4; i++)
#pragma unroll
        for (int j = 0; j < 4; j++) acc[i][j] = (f32x4){0.f, 0.f, 0.f, 0.f};

    for (int kk = 0; kk < ksize; kk += 32) {
        __syncthreads();
#pragma unroll
        for (int p = 0; p < 4; p++) {
            float4 v = *(const float4*)(aptr + (size_t)(p * 32) * N_NODES + kk);
            unsigned int h0 = f2bf(v.x), h1 = f2bf(v.y), h2 = f2bf(v.z), h3 = f2bf(v.w);
            unsigned int l0 = f2bf(v.x - bf2f(h0)), l1 = f2bf(v.y - bf2f(h1));
            unsigned int l2 = f2bf(v.z - bf2f(h2)), l3 = f2bf(v.w - bf2f(h3));
            int off = aoff + p * 32 * 32;
            *(uint2*)&ah[off] = make_uint2(h0 | (h1 << 16), h2 | (h3 << 16));
            *(uint2*)&al[off] = make_uint2(l0 | (l1 << 16), l2 | (l3 << 16));
        }
#pragma unroll
        for (int p = 0; p < 2; p++) {
            size_t go = bgo + (size_t)(p * 64) * N_NODES + kk;
            int off = boff + p * 256 * 8;
            *(uint4*)&bh[off] = *(const uint4*)(sTh + go);
            *(uint4*)&bl[off] = *(const uint4*)(sTl + go);
        }
        __syncthreads();

        bf16x8 Ah[4], Al[4], Bh[4], Bl[4];
#pragma unroll
        for (int i = 0; i < 4; i++) {
            Ah[i] = *(const bf16x8*)&ah[afb + i * 16 * 32];
            Al[i] = *(const bf16x8*)&al[afb + i * 16 * 32];
            Bh[i] = *(const bf16x8*)&bh[bfb + i * 16 * 32];
            Bl[i] = *(const bf16x8*)&bl[bfb + i * 16 * 32];
        }
#pragma unroll
        for (int i = 0; i < 4; i++)
#pragma unroll
            for (int j = 0; j < 4; j++) {
                acc[i][j] = __builtin_amdgcn_mfma_f32_16x16x32_bf16(Ah[i], Bh[j], acc[i][j], 0, 0, 0);
                acc[i][j] = __builtin_amdgcn_mfma_f32_16x16x32_bf16(Al[i], Bh[j], acc[i][j], 0, 0, 0);
                acc[i][j] = __builtin_amdgcn_mfma_f32_16x16x32_bf16(Ah[i], Bl[j], acc[i][j], 0, 0, 0);
            }
    }

    float* P = part + (size_t)blockIdx.y * N_NODES * HID;
#pragma unroll
    for (int i = 0; i < 4; i++)
#pragma unroll
        for (int j = 0; j < 4; j++)
#pragma unroll
            for (int r = 0; r < 4; r++) {
                int row = m0 + wm * 64 + i * 16 + quad * 4 + r;
                int col = wn * 64 + j * 16 + l16;
                P[(size_t)row * HID + col] = acc[i][j][r];
            }
}

// -------- kernel 3: reduce K-splits + bias + leaky_relu + segment_max --------
__global__ void pool_kernel(const float* __restrict__ part, int nsplit,
                            const float* __restrict__ bg,
                            const int* __restrict__ nn,
                            float* __restrict__ g) {
    const int gr = blockIdx.x, c = threadIdx.x;
    int start = 0;
    for (int i = 0; i < gr; i++) start += nn[i];
    const int len = nn[gr];
    float m = -FLT_MAX;
    for (int i = 0; i < len; i++) {
        size_t off = (size_t)(start + i) * HID + c;
        float v = bg[c];
        for (int s = 0; s < nsplit; s++) v += part[(size_t)s * N_NODES * HID + off];
        m = fmaxf(m, v > 0.f ? v : 0.01f * v);
    }
    g[gr * HID + c] = m;
}

// -------- kernel 4/5: out[r][c] = leaky(in[r,:] . W[c,:] + b[c]) --------
__global__ void layer_kernel(const float* __restrict__ in, const float* __restrict__ W,
                             const float* __restrict__ b, float* __restrict__ outp) {
    __shared__ float row[HID];
    const int r = blockIdx.x, c = threadIdx.x;
    row[c] = in[r * HID + c];
    __syncthreads();
    const float4* W4 = (const float4*)(W + (size_t)c * HID);
    float acc = 0.f;
#pragma unroll
    for (int i = 0; i < HID / 4; i++) {
        float4 wv = W4[i];
        acc += row[4 * i] * wv.x + row[4 * i + 1] * wv.y + row[4 * i + 2] * wv.z + row[4 * i + 3] * wv.w;
    }
    acc += b[c];
    outp[r * HID + c] = acc > 0.f ? acc : 0.01f * acc;
}

// -------- kernel 6: final [64,2] --------
__global__ void out_kernel(const float* __restrict__ in, const float* __restrict__ Wo,
                           const float* __restrict__ bo, float* __restrict__ outp) {
    const int t = threadIdx.x;
    const int r = t >> 1, c = t & 1;
    const float* row = in + r * HID;
    const float* wr = Wo + c * HID;
    float acc = 0.f;
#pragma unroll
    for (int i = 0; i < HID; i++) acc += row[i] * wr[i];
    outp[t] = acc + bo[c];
}

extern "C" void kernel_launch(void* const* d_in, const int* in_sizes, int n_in,
                              void* d_out, int out_size, void* d_ws, size_t ws_size,
                              hipStream_t stream) {
    (void)in_sizes; (void)n_in; (void)out_size;
    const float* x     = (const float*)d_in[0];
    const float* adj   = (const float*)d_in[1];
    const float* W_gcn = (const float*)d_in[2];
    const float* b_gcn = (const float*)d_in[3];
    const float* W_l1  = (const float*)d_in[4];
    const float* b_l1  = (const float*)d_in[5];
    const float* W_l2  = (const float*)d_in[6];
    const float* b_l2  = (const float*)d_in[7];
    const float* W_out = (const float*)d_in[8];
    const float* b_out = (const float*)d_in[9];
    const int* n_nodes = (const int*)d_in[11];
    float* out = (float*)d_out;

    char* w = (char*)d_ws;
    const size_t SZ_ST   = (size_t)HID * N_NODES * sizeof(unsigned short); // 4 MB each
    const size_t PART_OFF = 2 * SZ_ST;
    const size_t SZ_PART = (size_t)N_NODES * HID * sizeof(float);          // 8 MB per split
    const size_t SMALL   = (size_t)3 * NGRAPH * HID * sizeof(float) + 1024;
    int KS = 4;
    while (KS > 1 && PART_OFF + (size_t)KS * SZ_PART + SMALL > ws_size) KS >>= 1;

    unsigned short* sTh = (unsigned short*)w;
    unsigned short* sTl = (unsigned short*)(w + SZ_ST);
    float* part = (float*)(w + PART_OFF);
    float* sup  = part;  // aliased: consumed by split_kernel before gemm writes partials
    float* gbuf = (float*)(w + PART_OFF + (size_t)KS * SZ_PART);
    float* o1   = gbuf + NGRAPH * HID;
    float* o2   = o1 + NGRAPH * HID;

    support_kernel<<<dim3(N_NODES * HID / 256), 256, 0, stream>>>(x, W_gcn, sup);
    split_kernel<<<dim3(N_NODES / 128), 256, 0, stream>>>(sup, sTh, sTl);
    gemm_kernel<<<dim3(N_NODES / 128, KS), 256, 0, stream>>>(adj, sTh, sTl, part, N_NODES / KS);
    pool_kernel<<<dim3(NGRAPH), 128, 0, stream>>>(part, KS, b_gcn, n_nodes, gbuf);
    layer_kernel<<<dim3(NGRAPH), 128, 0, stream>>>(gbuf, W_l1, b_l1, o1);
    layer_kernel<<<dim3(NGRAPH), 128, 0, stream>>>(o1, W_l2, b_l2, o2);
    out_kernel<<<1, 128, 0, stream>>>(o2, W_out, b_out, out);
}